// Round 2
// baseline (1161.664 us; speedup 1.0000x reference)
//
#include <hip/hip_runtime.h>

typedef __bf16 bf16x8 __attribute__((ext_vector_type(8)));
typedef float f32x4 __attribute__((ext_vector_type(4)));

#define GPTR(p) ((const __attribute__((address_space(1))) void*)(p))
#define LPTR(p) ((__attribute__((address_space(3))) void*)(p))

static __device__ __forceinline__ ushort f2bf(float f) {
  uint u = __builtin_bit_cast(uint, f);
  u += 0x7fffu + ((u >> 16) & 1u);
  return (ushort)(u >> 16);
}
static __device__ __forceinline__ float bf2f(ushort h) {
  uint u = ((uint)h) << 16;
  return __builtin_bit_cast(float, u);
}

// ------------------------------------------------- per-array dtype detection
__global__ void detect9(const ushort* p0, const ushort* p1, const ushort* p2,
                        const ushort* p3, const ushort* p4, const ushort* p5,
                        const ushort* p6, const ushort* p7, const ushort* p8,
                        int* flags) {
  const ushort* ps[9] = {p0, p1, p2, p3, p4, p5, p6, p7, p8};
  const ushort* p = ps[blockIdx.x];
  int t = threadIdx.x;  // 64 threads
  ushort u = p[2 * t];
  int e = (u >> 7) & 0xFF;
  int sane = (e >= 100 && e <= 150) ? 1 : 0;
  unsigned long long m = __ballot(sane);
  if (t == 0) flags[blockIdx.x] = (__popcll(m) >= 48) ? 0 : 1;
}

static __device__ __forceinline__ float ldf(const void* p, int is32, size_t i) {
  return is32 ? ((const float*)p)[i] : bf2f(((const ushort*)p)[i]);
}

// ---------------------------------------------------------------- transpose W -> bf16 WT[d][k]
__global__ void transw(const void* W, ushort* __restrict__ WT,
                       const int* __restrict__ flags, int fi, int F) {
  int is32 = flags[fi];
  int i = blockIdx.x * 256 + threadIdx.x;   // i = k*256 + d
  int k = i >> 8, d = i & 255;
  ushort v = is32 ? f2bf(((const float*)W)[i]) : ((const ushort*)W)[i];
  WT[(size_t)d * F + k] = v;
}

// ---------------------------------------------------------------- wa[j][k] = sum_d W[k][d]*a_j[d]
__global__ __launch_bounds__(256) void wa_k(const void* W, const void* a1, const void* a2,
                                            const void* a3, const int* __restrict__ flags,
                                            int fW, int f1, int f2, int f3,
                                            float* __restrict__ wa, int F) {
  __shared__ float al[3][256];
  int t = threadIdx.x;
  al[0][t] = ldf(a1, flags[f1], t);
  al[1][t] = ldf(a2, flags[f2], t);
  al[2][t] = ldf(a3, flags[f3], t);
  __syncthreads();
  int k = blockIdx.x * 256 + t;
  if (k < F) {
    int w32 = flags[fW];
    float s0 = 0.f, s1 = 0.f, s2 = 0.f;
    for (int d = 0; d < 256; d++) {
      float wv = ldf(W, w32, (size_t)k * 256 + d);
      s0 += wv * al[0][d]; s1 += wv * al[1][d]; s2 += wv * al[2][d];
    }
    wa[k] = s0; wa[F + k] = s1; wa[2 * F + k] = s2;
  }
}

// ---------------------------------------------------------------- e-vectors straight from x (fp32): e = x @ wa
__global__ __launch_bounds__(256) void evec_x(const void* __restrict__ x,
                                              const float* __restrict__ wa,
                                              const int* __restrict__ flags, int fi,
                                              float* __restrict__ o1, float* __restrict__ o2,
                                              float* __restrict__ o3, int F) {
  int x32 = flags[fi];
  int node = blockIdx.x * 4 + (threadIdx.x >> 6);   // one wave per node
  int lane = threadIdx.x & 63;
  const float* wa1 = wa, *wa2 = wa + F, *wa3 = wa + 2 * F;
  float s1 = 0.f, s2 = 0.f, s3 = 0.f;
  size_t base = (size_t)node * F;
  for (int k = lane; k < F; k += 64) {
    float xv = ldf(x, x32, base + k);
    s1 += xv * wa1[k]; s2 += xv * wa2[k]; s3 += xv * wa3[k];
  }
  #pragma unroll
  for (int off = 1; off < 64; off <<= 1) {
    s1 += __shfl_xor(s1, off); s2 += __shfl_xor(s2, off); s3 += __shfl_xor(s3, off);
  }
  if (lane == 0) { o1[node] = s1; o2[node] = s2; o3[node] = s3; }
}

// ---- DMA-stage a 256x64 bf16 tile (row-major src, rowstride in elems) into
// linear LDS [256][64] with XOR-swizzled 16B slots:
//   element (d, k) lives at LDS ushort offset d*64 + (k ^ ((d&7)<<3))
// achieved by pre-swizzling the per-lane GLOBAL source address (linear LDS dest,
// wave-uniform base + lane*16, as global_load_lds requires). Both-sides
// pattern (rule 21): source permutation == read permutation (involution).
static __device__ __forceinline__ void stage_tile(const ushort* __restrict__ src,
                                                  int rowstride,
                                                  ushort* __restrict__ dst,
                                                  int wave, int lane) {
  int rsub = lane >> 3;                       // 0..7 (row within 8-row stripe)
  int gsw = ((lane & 7) ^ rsub) << 3;         // swizzled col offset (elems)
  #pragma unroll
  for (int i = 0; i < 8; i++) {
    int dbase = i * 32 + wave * 8;            // wave-uniform row base (mult of 8)
    __builtin_amdgcn_global_load_lds(
        GPTR(src + (size_t)(dbase + rsub) * rowstride + gsw),
        LPTR(dst + dbase * 64), 16, 0, 0);
  }
}

// x-tile (64 rows x 64 cols) -> 4 (fp32) / 2 (bf16) uint4 regs per thread
static __device__ __forceinline__ void load_x4(uint4* dst, const void* x, int x32,
                                               size_t rowbase, int F, int k0,
                                               int r0, int g8) {
  if (x32) {
    #pragma unroll
    for (int i = 0; i < 2; i++) {
      const uint4* xf = (const uint4*)((const float*)x + (rowbase + (size_t)(r0 + i * 32)) * F + k0);
      dst[2 * i] = xf[2 * g8]; dst[2 * i + 1] = xf[2 * g8 + 1];
    }
  } else {
    #pragma unroll
    for (int i = 0; i < 2; i++) {
      const uint4* xb = (const uint4*)((const ushort*)x + (rowbase + (size_t)(r0 + i * 32)) * F + k0);
      dst[i] = xb[g8];
    }
  }
}

// ---------------------------------------------------------------- h = x @ W  (writes hT[b][d][n], bf16)
__global__ __launch_bounds__(256) void gemm_h(const void* __restrict__ x,
                                              const ushort* __restrict__ WT,
                                              ushort* __restrict__ hT,
                                              const int* __restrict__ flags, int fi,
                                              int N, int F) {
  int x32 = flags[fi];
  int ntiles = N >> 6;
  int b  = blockIdx.x / ntiles;
  int n0 = (blockIdx.x % ntiles) << 6;
  __shared__ ushort Al[64][72];      // x tile [n][k], padded (VALU-written)
  __shared__ ushort Bl[256 * 64];    // WT tile, linear + XOR-swizzled (DMA-written)
  int t = threadIdx.x, wave = t >> 6, lane = t & 63;
  int r0 = t >> 3, g8 = t & 7;
  size_t rowbase = (size_t)(b * N + n0);
  f32x4 acc[4][4] = {};

  const int nk = F >> 6;
  uint4 xr[4], xn[4];
  load_x4(xr, x, x32, rowbase, F, 0, r0, g8);   // prologue: x regs for tile 0

  for (int kt = 0; kt < nk; kt++) {
    int k0 = kt << 6;
    int has_next = (kt + 1 < nk);
    // 1. DMA-stage current B tile (latency hides under the convert phase)
    stage_tile(WT + k0, F, Bl, wave, lane);
    // 2. prefetch next x tile into regs (issued early; latency hides under
    //    convert + this tile's MFMA-side of the barrier drain)
    if (has_next) load_x4(xn, x, x32, rowbase, F, k0 + 64, r0, g8);
    // 3. convert cur x regs -> Al
    if (x32) {
      #pragma unroll
      for (int i = 0; i < 2; i++) {
        union { uint4 q[2]; float f[8]; } fa;
        fa.q[0] = xr[2 * i]; fa.q[1] = xr[2 * i + 1];
        union { ushort u[8]; uint4 q; } pk;
        #pragma unroll
        for (int j = 0; j < 8; j++) pk.u[j] = f2bf(fa.f[j]);
        ((uint4*)&Al[r0 + i * 32][0])[g8] = pk.q;
      }
    } else {
      #pragma unroll
      for (int i = 0; i < 2; i++) ((uint4*)&Al[r0 + i * 32][0])[g8] = xr[i];
    }
    // 4. verified m97 sync pattern: full drain + barrier
    __syncthreads();
    // 5. MFMA
    #pragma unroll
    for (int kh = 0; kh < 2; kh++) {
      int kk = kh * 32 + ((lane >> 4) << 3);
      int sw = (lane & 7) << 3;
      bf16x8 af[4], bfr[4];
      #pragma unroll
      for (int rf = 0; rf < 4; rf++) af[rf]  = *(const bf16x8*)&Al[rf * 16 + (lane & 15)][kk];
      #pragma unroll
      for (int cf = 0; cf < 4; cf++) {
        int d = wave * 64 + cf * 16 + (lane & 15);
        bfr[cf] = *(const bf16x8*)(Bl + d * 64 + (kk ^ sw));   // (d&7)<<3 == sw
      }
      #pragma unroll
      for (int rf = 0; rf < 4; rf++)
        #pragma unroll
        for (int cf = 0; cf < 4; cf++)
          acc[rf][cf] = __builtin_amdgcn_mfma_f32_16x16x32_bf16(af[rf], bfr[cf], acc[rf][cf], 0, 0, 0);
    }
    __syncthreads();
    if (has_next) {
      #pragma unroll
      for (int j = 0; j < 4; j++) xr[j] = xn[j];
    }
  }
  #pragma unroll
  for (int rf = 0; rf < 4; rf++) {
    int n = n0 + rf * 16 + ((lane >> 4) << 2);
    #pragma unroll
    for (int cf = 0; cf < 4; cf++) {
      int d = wave * 64 + cf * 16 + (lane & 15);
      ushort4 v;
      v.x = f2bf(acc[rf][cf][0]); v.y = f2bf(acc[rf][cf][1]);
      v.z = f2bf(acc[rf][cf][2]); v.w = f2bf(acc[rf][cf][3]);
      *(ushort4*)(hT + ((size_t)b * 256 + d) * N + n) = v;
    }
  }
}

// ---------------------------------------------------------------- fused masked-softmax attention (one adj pass)
__global__ __launch_bounds__(256) void att(const float* __restrict__ e1,
                                           const float* __restrict__ e2,
                                           const ushort* __restrict__ gT,
                                           const int* __restrict__ adj,
                                           const void* bias,
                                           const int* __restrict__ flags,
                                           void* __restrict__ outv, size_t ooff,
                                           int Nr, int M) {
  int b32 = flags[8];
  int o32 = flags[0] | flags[1] | flags[2] | flags[3] | flags[4] |
            flags[5] | flags[6] | flags[7] | flags[8];
  int ntiles = Nr >> 6;
  int b  = blockIdx.x / ntiles;
  int n0 = (blockIdx.x % ntiles) << 6;
  __shared__ ushort Wl[64][72];      // weight tile (VALU-written, padded)
  __shared__ ushort Gl[256 * 64];    // g tile, linear + XOR-swizzled (DMA-written)
  __shared__ float  e2l[1024];
  __shared__ float  e1l[64];
  __shared__ float  rscale[64];
  int t = threadIdx.x, wave = t >> 6, lane = t & 63;
  for (int i = t; i < M; i += 256) e2l[i] = e2[(size_t)b * M + i];
  if (t < 64) e1l[t] = e1[(size_t)b * Nr + n0 + t];
  __syncthreads();

  f32x4 acc[4][4] = {};
  float s_part = 0.f, deg_part = 0.f;
  int r = t >> 2, mseg = (t & 3) << 4;
  float e1v = e1l[r];
  const int* adjrow = adj + ((size_t)b * Nr + n0 + r) * M;
  const ushort* gbase = gT + (size_t)b * 256 * M;

  // prologue: prefetch adj for tile 0
  int4 qc0 = ((const int4*)(adjrow + mseg))[0];
  int4 qc1 = ((const int4*)(adjrow + mseg))[1];
  int4 qc2 = ((const int4*)(adjrow + mseg))[2];
  int4 qc3 = ((const int4*)(adjrow + mseg))[3];

  const int nm = M >> 6;
  for (int mt = 0; mt < nm; mt++) {
    int m0 = mt << 6;
    int has_next = (mt + 1 < nm);
    // 1. DMA-stage current g tile (latency hides under the weight compute)
    stage_tile(gbase + m0, M, Gl, wave, lane);
    // 2. prefetch next adj segment (HBM latency hides under this tile's work)
    int4 qn0, qn1, qn2, qn3;
    if (has_next) {
      const int* apn = adjrow + m0 + 64 + mseg;
      qn0 = ((const int4*)apn)[0]; qn1 = ((const int4*)apn)[1];
      qn2 = ((const int4*)apn)[2]; qn3 = ((const int4*)apn)[3];
    }
    // 3. weight compute from prefetched adj regs
    {
      int av[16] = {qc0.x,qc0.y,qc0.z,qc0.w, qc1.x,qc1.y,qc1.z,qc1.w,
                    qc2.x,qc2.y,qc2.z,qc2.w, qc3.x,qc3.y,qc3.z,qc3.w};
      union { ushort u[16]; uint4 q[2]; } pk;
      #pragma unroll
      for (int j = 0; j < 16; j++) {
        float e = e1v + e2l[m0 + mseg + j];
        e = e > 0.f ? e : 0.2f * e;
        e = fminf(e, 60.f);
        float w = (av[j] > 0) ? __expf(e) : 0.f;
        ushort wb = f2bf(w);
        s_part += bf2f(wb);      // sum exactly what the MFMA sums
        deg_part += (float)av[j];
        pk.u[j] = wb;
      }
      *(uint4*)&Wl[r][mseg]     = pk.q[0];
      *(uint4*)&Wl[r][mseg + 8] = pk.q[1];
    }
    // 4. verified m97 sync pattern: full drain + barrier
    __syncthreads();
    // 5. MFMA
    #pragma unroll
    for (int kh = 0; kh < 2; kh++) {
      int kk = kh * 32 + ((lane >> 4) << 3);
      int sw = (lane & 7) << 3;
      bf16x8 af[4], bfr[4];
      #pragma unroll
      for (int rf = 0; rf < 4; rf++) af[rf]  = *(const bf16x8*)&Wl[rf * 16 + (lane & 15)][kk];
      #pragma unroll
      for (int cf = 0; cf < 4; cf++) {
        int d = wave * 64 + cf * 16 + (lane & 15);
        bfr[cf] = *(const bf16x8*)(Gl + d * 64 + (kk ^ sw));   // (d&7)<<3 == sw
      }
      #pragma unroll
      for (int rf = 0; rf < 4; rf++)
        #pragma unroll
        for (int cf = 0; cf < 4; cf++)
          acc[rf][cf] = __builtin_amdgcn_mfma_f32_16x16x32_bf16(af[rf], bfr[cf], acc[rf][cf], 0, 0, 0);
    }
    __syncthreads();
    if (has_next) { qc0 = qn0; qc1 = qn1; qc2 = qn2; qc3 = qn3; }
  }

  s_part   += __shfl_xor(s_part, 1);   s_part   += __shfl_xor(s_part, 2);
  deg_part += __shfl_xor(deg_part, 1); deg_part += __shfl_xor(deg_part, 2);
  if ((t & 3) == 0) {
    float sc = (s_part > 0.f) ? deg_part / s_part : 0.f;
    if (!(sc > -1e38f && sc < 1e38f)) sc = 0.f;
    rscale[r] = sc;
  }
  __syncthreads();

  #pragma unroll
  for (int rf = 0; rf < 4; rf++) {
    int nbase = rf * 16 + ((lane >> 4) << 2);
    #pragma unroll
    for (int cf = 0; cf < 4; cf++) {
      int d = wave * 64 + cf * 16 + (lane & 15);
      float bi = ldf(bias, b32, d);
      #pragma unroll
      for (int j = 0; j < 4; j++) {
        int nl = nbase + j;
        float v = acc[rf][cf][j] * rscale[nl] + bi;
        size_t idx = ooff + ((size_t)(b * Nr + n0 + nl)) * 256 + d;
        if (o32) ((float*)outv)[idx] = v;
        else     ((ushort*)outv)[idx] = f2bf(v);
      }
    }
  }
}

// ---------------------------------------------------------------- launch
extern "C" void kernel_launch(void* const* d_in, const int* in_sizes, int n_in,
                              void* d_out, int out_size, void* d_ws, size_t ws_size,
                              hipStream_t stream) {
  (void)in_sizes; (void)n_in; (void)out_size; (void)ws_size;
  const void* x0   = d_in[0];
  const void* x1   = d_in[1];
  const void* W0   = d_in[2];
  const void* W1   = d_in[3];
  const void* a1_0 = d_in[4];
  const void* a2_0 = d_in[5];
  const void* a1_1 = d_in[6];
  const void* a2_1 = d_in[7];
  const void* bias = d_in[8];
  const int* adj00 = (const int*)d_in[9];
  const int* adj01 = (const int*)d_in[10];
  const int* adj10 = (const int*)d_in[11];
  const int* adj11 = (const int*)d_in[12];

  const int B = 64, N1 = 1024, N2 = 512, F0 = 512, F1 = 384;
  int*    flags = (int*)d_ws;                               // 16 ints
  ushort* base = (ushort*)((char*)d_ws + 64);
  ushort* hT0 = base;                                       // [B,256,N1] bf16
  ushort* hT1 = hT0 + (size_t)B * 256 * N1;                 // [B,256,N2] bf16
  ushort* WT0 = hT1 + (size_t)B * 256 * N2;                 // [256,F0]
  ushort* WT1 = WT0 + (size_t)256 * F0;                     // [256,F1]
  float* e1_0 = (float*)(WT1 + (size_t)256 * F1);           // [B,N1]
  float* e2a  = e1_0 + (size_t)B * N1;
  float* e2c  = e2a + (size_t)B * N1;
  float* e1_1 = e2c + (size_t)B * N1;                       // [B,N2]
  float* e2b  = e1_1 + (size_t)B * N2;
  float* e2d  = e2b + (size_t)B * N2;
  float* wa0  = e2d + (size_t)B * N2;                       // [3,F0]
  float* wa1  = wa0 + 3 * F0;                               // [3,F1]

  detect9<<<9, 64, 0, stream>>>((const ushort*)x0, (const ushort*)x1,
                                (const ushort*)W0, (const ushort*)W1,
                                (const ushort*)a1_0, (const ushort*)a2_0,
                                (const ushort*)a1_1, (const ushort*)a2_1,
                                (const ushort*)bias, flags);

  transw<<<F0, 256, 0, stream>>>(W0, WT0, flags, 2, F0);
  transw<<<F1, 256, 0, stream>>>(W1, WT1, flags, 3, F1);
  wa_k<<<(F0 + 255) / 256, 256, 0, stream>>>(W0, a1_0, a2_0, a2_1, flags, 2, 4, 5, 7, wa0, F0);
  wa_k<<<(F1 + 255) / 256, 256, 0, stream>>>(W1, a1_1, a2_0, a2_1, flags, 3, 6, 5, 7, wa1, F1);
  gemm_h<<<B * (N1 / 64), 256, 0, stream>>>(x0, WT0, hT0, flags, 0, N1, F0);
  gemm_h<<<B * (N2 / 64), 256, 0, stream>>>(x1, WT1, hT1, flags, 1, N2, F1);
  evec_x<<<B * N1 / 4, 256, 0, stream>>>(x0, wa0, flags, 0, e1_0, e2a, e2c, F0);
  evec_x<<<B * N2 / 4, 256, 0, stream>>>(x1, wa1, flags, 1, e1_1, e2b, e2d, F1);

  const size_t o00 = 0;
  const size_t o01 = (size_t)B * N1 * 256;
  const size_t o10 = o01 + (size_t)B * N1 * 256;
  const size_t o11 = o10 + (size_t)B * N2 * 256;
  att<<<B * (N1 / 64), 256, 0, stream>>>(e1_0, e2a, hT0, adj00, bias, flags, d_out, o00, N1, N1);
  att<<<B * (N1 / 64), 256, 0, stream>>>(e1_0, e2b, hT1, adj01, bias, flags, d_out, o01, N1, N2);
  att<<<B * (N2 / 64), 256, 0, stream>>>(e1_1, e2c, hT0, adj10, bias, flags, d_out, o10, N2, N1);
  att<<<B * (N2 / 64), 256, 0, stream>>>(e1_1, e2d, hT1, adj11, bias, flags, d_out, o11, N2, N2);
}

// Round 5
// 1032.833 us; speedup vs baseline: 1.1247x; 1.1247x over previous
//
#include <hip/hip_runtime.h>

typedef __bf16 bf16x8 __attribute__((ext_vector_type(8)));
typedef float f32x4 __attribute__((ext_vector_type(4)));

static __device__ __forceinline__ ushort f2bf(float f) {
  uint u = __builtin_bit_cast(uint, f);
  u += 0x7fffu + ((u >> 16) & 1u);
  return (ushort)(u >> 16);
}
static __device__ __forceinline__ float bf2f(ushort h) {
  uint u = ((uint)h) << 16;
  return __builtin_bit_cast(float, u);
}

// ------------------------------------------------- per-array dtype detection
__global__ void detect9(const ushort* p0, const ushort* p1, const ushort* p2,
                        const ushort* p3, const ushort* p4, const ushort* p5,
                        const ushort* p6, const ushort* p7, const ushort* p8,
                        int* flags) {
  const ushort* ps[9] = {p0, p1, p2, p3, p4, p5, p6, p7, p8};
  const ushort* p = ps[blockIdx.x];
  int t = threadIdx.x;  // 64 threads
  ushort u = p[2 * t];
  int e = (u >> 7) & 0xFF;
  int sane = (e >= 100 && e <= 150) ? 1 : 0;
  unsigned long long m = __ballot(sane);
  if (t == 0) flags[blockIdx.x] = (__popcll(m) >= 48) ? 0 : 1;
}

static __device__ __forceinline__ float ldf(const void* p, int is32, size_t i) {
  return is32 ? ((const float*)p)[i] : bf2f(((const ushort*)p)[i]);
}

// ---------------------------------------------------------------- transpose W -> bf16 WT[d][k]
__global__ void transw(const void* W, ushort* __restrict__ WT,
                       const int* __restrict__ flags, int fi, int F) {
  int is32 = flags[fi];
  int i = blockIdx.x * 256 + threadIdx.x;   // i = k*256 + d
  int k = i >> 8, d = i & 255;
  ushort v = is32 ? f2bf(((const float*)W)[i]) : ((const ushort*)W)[i];
  WT[(size_t)d * F + k] = v;
}

// ---------------------------------------------------------------- wa[j][k] = sum_d W[k][d]*a_j[d]  (fp32 exact)
__global__ __launch_bounds__(256) void wa_k(const void* W, const void* a1, const void* a2,
                                            const void* a3, const int* __restrict__ flags,
                                            int fW, int f1, int f2, int f3,
                                            float* __restrict__ wa, int F) {
  __shared__ float al[3][256];
  int t = threadIdx.x;
  al[0][t] = ldf(a1, flags[f1], t);
  al[1][t] = ldf(a2, flags[f2], t);
  al[2][t] = ldf(a3, flags[f3], t);
  __syncthreads();
  int k = blockIdx.x * 256 + t;
  if (k < F) {
    int w32 = flags[fW];
    float s0 = 0.f, s1 = 0.f, s2 = 0.f;
    for (int d = 0; d < 256; d++) {
      float wv = ldf(W, w32, (size_t)k * 256 + d);
      s0 += wv * al[0][d]; s1 += wv * al[1][d]; s2 += wv * al[2][d];
    }
    wa[k] = s0; wa[F + k] = s1; wa[2 * F + k] = s2;
  }
}

// ---------------------------------------------------------------- e-vectors straight from x (fp32): e = x @ wa
__global__ __launch_bounds__(256) void evec_x(const void* __restrict__ x,
                                              const float* __restrict__ wa,
                                              const int* __restrict__ flags, int fi,
                                              float* __restrict__ o1, float* __restrict__ o2,
                                              float* __restrict__ o3, int F) {
  int x32 = flags[fi];
  int node = blockIdx.x * 4 + (threadIdx.x >> 6);   // one wave per node
  int lane = threadIdx.x & 63;
  const float* wa1 = wa, *wa2 = wa + F, *wa3 = wa + 2 * F;
  float s1 = 0.f, s2 = 0.f, s3 = 0.f;
  size_t base = (size_t)node * F;
  for (int k = lane; k < F; k += 64) {
    float xv = ldf(x, x32, base + k);
    s1 += xv * wa1[k]; s2 += xv * wa2[k]; s3 += xv * wa3[k];
  }
  #pragma unroll
  for (int off = 1; off < 64; off <<= 1) {
    s1 += __shfl_xor(s1, off); s2 += __shfl_xor(s2, off); s3 += __shfl_xor(s3, off);
  }
  if (lane == 0) { o1[node] = s1; o2[node] = s2; o3[node] = s3; }
}

// ---------------------------------------------------------------- h = x @ W  (writes hT[b][d][n], bf16)
__global__ __launch_bounds__(256) void gemm_h(const void* __restrict__ x,
                                              const ushort* __restrict__ WT,
                                              ushort* __restrict__ hT,
                                              const int* __restrict__ flags, int fi,
                                              int N, int F) {
  int x32 = flags[fi];
  int ntiles = N >> 6;
  int b  = blockIdx.x / ntiles;
  int n0 = (blockIdx.x % ntiles) << 6;
  __shared__ ushort Al[64][72];    // x tile [n][k]
  __shared__ ushort Bl[256][72];   // WT tile [d][k]
  int t = threadIdx.x, wave = t >> 6, lane = t & 63;
  f32x4 acc[4][4] = {};

  for (int k0 = 0; k0 < F; k0 += 64) {
    #pragma unroll
    for (int i = 0; i < 2; i++) {
      int r = (t >> 3) + i * 32, g = t & 7;
      if (!x32) {
        const ushort* xb = (const ushort*)x + (size_t)(b * N + n0 + r) * F + k0;
        ((uint4*)&Al[r][0])[g] = ((const uint4*)xb)[g];
      } else {
        const float* xf = (const float*)x + (size_t)(b * N + n0 + r) * F + k0;
        float4 fa = ((const float4*)xf)[2 * g];
        float4 fb = ((const float4*)xf)[2 * g + 1];
        union { ushort u[8]; uint4 q; } pk;
        pk.u[0] = f2bf(fa.x); pk.u[1] = f2bf(fa.y); pk.u[2] = f2bf(fa.z); pk.u[3] = f2bf(fa.w);
        pk.u[4] = f2bf(fb.x); pk.u[5] = f2bf(fb.y); pk.u[6] = f2bf(fb.z); pk.u[7] = f2bf(fb.w);
        ((uint4*)&Al[r][0])[g] = pk.q;
      }
    }
    #pragma unroll
    for (int i = 0; i < 8; i++) {
      int d = (t >> 3) + i * 32, g = t & 7;
      ((uint4*)&Bl[d][0])[g] = ((const uint4*)(WT + (size_t)d * F + k0))[g];
    }
    __syncthreads();
    #pragma unroll
    for (int kh = 0; kh < 2; kh++) {
      int kk = kh * 32 + ((lane >> 4) << 3);
      bf16x8 af[4], bfr[4];
      #pragma unroll
      for (int rf = 0; rf < 4; rf++) af[rf]  = *(const bf16x8*)&Al[rf * 16 + (lane & 15)][kk];
      #pragma unroll
      for (int cf = 0; cf < 4; cf++) bfr[cf] = *(const bf16x8*)&Bl[wave * 64 + cf * 16 + (lane & 15)][kk];
      #pragma unroll
      for (int rf = 0; rf < 4; rf++)
        #pragma unroll
        for (int cf = 0; cf < 4; cf++)
          acc[rf][cf] = __builtin_amdgcn_mfma_f32_16x16x32_bf16(af[rf], bfr[cf], acc[rf][cf], 0, 0, 0);
    }
    __syncthreads();
  }
  #pragma unroll
  for (int rf = 0; rf < 4; rf++) {
    int n = n0 + rf * 16 + ((lane >> 4) << 2);
    #pragma unroll
    for (int cf = 0; cf < 4; cf++) {
      int d = wave * 64 + cf * 16 + (lane & 15);
      ushort4 v;
      v.x = f2bf(acc[rf][cf][0]); v.y = f2bf(acc[rf][cf][1]);
      v.z = f2bf(acc[rf][cf][2]); v.w = f2bf(acc[rf][cf][3]);
      *(ushort4*)(hT + ((size_t)b * 256 + d) * N + n) = v;
    }
  }
}

// ---------------------------------------------------------------- fused masked-softmax attention (one adj pass)
// XCD-grouping swizzle: all n-tiles of a given batch b land on ONE XCD
// (wgid % 8 constant within the b-group), so gT[b] (256..512 KB) is fetched
// into that XCD's L2 once per b instead of once per XCD per b / once per
// block. Bijective: grid = 64*ntiles, ntiles in {8,16}, both divisible by 8.
__global__ __launch_bounds__(256) void att(const float* __restrict__ e1,
                                           const float* __restrict__ e2,
                                           const ushort* __restrict__ gT,
                                           const int* __restrict__ adj,
                                           const void* bias,
                                           const int* __restrict__ flags,
                                           void* __restrict__ outv, size_t ooff,
                                           int Nr, int M) {
  int b32 = flags[8];
  int o32 = flags[0] | flags[1] | flags[2] | flags[3] | flags[4] |
            flags[5] | flags[6] | flags[7] | flags[8];   // jax promotion: any fp32 -> fp32 out
  int ntiles = Nr >> 6;
  int lt = __builtin_ctz(ntiles);            // ntiles is 8 or 16
  int wg = blockIdx.x;
  int c = wg & 7, j = wg >> 3;               // c = XCD (round-robin assumption)
  int b  = c * 8 + (j >> lt);                // b in [8c, 8c+8)
  int n0 = (j & (ntiles - 1)) << 6;
  __shared__ ushort Wl[64][72];
  __shared__ ushort Gl[256][72];
  __shared__ float  e2l[1024];
  __shared__ float  e1l[64];
  __shared__ float  rscale[64];
  int t = threadIdx.x, wave = t >> 6, lane = t & 63;
  for (int i = t; i < M; i += 256) e2l[i] = e2[(size_t)b * M + i];
  if (t < 64) e1l[t] = e1[(size_t)b * Nr + n0 + t];
  __syncthreads();

  f32x4 acc[4][4] = {};
  float s_part = 0.f, deg_part = 0.f;
  int r = t >> 2, mseg = (t & 3) << 4;
  float e1v = e1l[r];
  const int* adjrow = adj + ((size_t)b * Nr + n0 + r) * M;

  for (int m0 = 0; m0 < M; m0 += 64) {
    #pragma unroll
    for (int i = 0; i < 8; i++) {
      int d = (t >> 3) + i * 32, g = t & 7;
      ((uint4*)&Gl[d][0])[g] = ((const uint4*)(gT + ((size_t)b * 256 + d) * M + m0))[g];
    }
    {
      const int* ap = adjrow + m0 + mseg;
      int4 q0 = ((const int4*)ap)[0], q1 = ((const int4*)ap)[1];
      int4 q2 = ((const int4*)ap)[2], q3 = ((const int4*)ap)[3];
      int av[16] = {q0.x,q0.y,q0.z,q0.w, q1.x,q1.y,q1.z,q1.w,
                    q2.x,q2.y,q2.z,q2.w, q3.x,q3.y,q3.z,q3.w};
      union { ushort u[16]; uint4 q[2]; } pk;
      #pragma unroll
      for (int jj = 0; jj < 16; jj++) {
        float e = e1v + e2l[m0 + mseg + jj];
        e = e > 0.f ? e : 0.2f * e;
        e = fminf(e, 60.f);
        float w = (av[jj] > 0) ? __expf(e) : 0.f;
        ushort wb = f2bf(w);
        s_part += bf2f(wb);      // sum exactly what the MFMA sums
        deg_part += (float)av[jj];
        pk.u[jj] = wb;
      }
      *(uint4*)&Wl[r][mseg]     = pk.q[0];
      *(uint4*)&Wl[r][mseg + 8] = pk.q[1];
    }
    __syncthreads();
    #pragma unroll
    for (int kh = 0; kh < 2; kh++) {
      int kk = kh * 32 + ((lane >> 4) << 3);
      bf16x8 af[4], bfr[4];
      #pragma unroll
      for (int rf = 0; rf < 4; rf++) af[rf]  = *(const bf16x8*)&Wl[rf * 16 + (lane & 15)][kk];
      #pragma unroll
      for (int cf = 0; cf < 4; cf++) bfr[cf] = *(const bf16x8*)&Gl[wave * 64 + cf * 16 + (lane & 15)][kk];
      #pragma unroll
      for (int rf = 0; rf < 4; rf++)
        #pragma unroll
        for (int cf = 0; cf < 4; cf++)
          acc[rf][cf] = __builtin_amdgcn_mfma_f32_16x16x32_bf16(af[rf], bfr[cf], acc[rf][cf], 0, 0, 0);
    }
    __syncthreads();
  }

  s_part   += __shfl_xor(s_part, 1);   s_part   += __shfl_xor(s_part, 2);
  deg_part += __shfl_xor(deg_part, 1); deg_part += __shfl_xor(deg_part, 2);
  if ((t & 3) == 0) {
    float sc = (s_part > 0.f) ? deg_part / s_part : 0.f;
    if (!(sc > -1e38f && sc < 1e38f)) sc = 0.f;
    rscale[r] = sc;
  }
  __syncthreads();

  #pragma unroll
  for (int rf = 0; rf < 4; rf++) {
    int nbase = rf * 16 + ((lane >> 4) << 2);
    #pragma unroll
    for (int cf = 0; cf < 4; cf++) {
      int d = wave * 64 + cf * 16 + (lane & 15);
      float bi = ldf(bias, b32, d);
      #pragma unroll
      for (int jj = 0; jj < 4; jj++) {
        int nl = nbase + jj;
        float v = acc[rf][cf][jj] * rscale[nl] + bi;
        size_t idx = ooff + ((size_t)(b * Nr + n0 + nl)) * 256 + d;
        if (o32) ((float*)outv)[idx] = v;
        else     ((ushort*)outv)[idx] = f2bf(v);
      }
    }
  }
}

// ---------------------------------------------------------------- launch
extern "C" void kernel_launch(void* const* d_in, const int* in_sizes, int n_in,
                              void* d_out, int out_size, void* d_ws, size_t ws_size,
                              hipStream_t stream) {
  (void)in_sizes; (void)n_in; (void)out_size; (void)ws_size;
  const void* x0   = d_in[0];
  const void* x1   = d_in[1];
  const void* W0   = d_in[2];
  const void* W1   = d_in[3];
  const void* a1_0 = d_in[4];
  const void* a2_0 = d_in[5];
  const void* a1_1 = d_in[6];
  const void* a2_1 = d_in[7];
  const void* bias = d_in[8];
  const int* adj00 = (const int*)d_in[9];
  const int* adj01 = (const int*)d_in[10];
  const int* adj10 = (const int*)d_in[11];
  const int* adj11 = (const int*)d_in[12];

  const int B = 64, N1 = 1024, N2 = 512, F0 = 512, F1 = 384;
  int*    flags = (int*)d_ws;                               // 16 ints
  ushort* base = (ushort*)((char*)d_ws + 64);
  ushort* hT0 = base;                                       // [B,256,N1] bf16
  ushort* hT1 = hT0 + (size_t)B * 256 * N1;                 // [B,256,N2] bf16
  ushort* WT0 = hT1 + (size_t)B * 256 * N2;                 // [256,F0]
  ushort* WT1 = WT0 + (size_t)256 * F0;                     // [256,F1]
  float* e1_0 = (float*)(WT1 + (size_t)256 * F1);           // [B,N1]
  float* e2a  = e1_0 + (size_t)B * N1;
  float* e2c  = e2a + (size_t)B * N1;
  float* e1_1 = e2c + (size_t)B * N1;                       // [B,N2]
  float* e2b  = e1_1 + (size_t)B * N2;
  float* e2d  = e2b + (size_t)B * N2;
  float* wa0  = e2d + (size_t)B * N2;                       // [3,F0]
  float* wa1  = wa0 + 3 * F0;                               // [3,F1]

  detect9<<<9, 64, 0, stream>>>((const ushort*)x0, (const ushort*)x1,
                                (const ushort*)W0, (const ushort*)W1,
                                (const ushort*)a1_0, (const ushort*)a2_0,
                                (const ushort*)a1_1, (const ushort*)a2_1,
                                (const ushort*)bias, flags);

  transw<<<F0, 256, 0, stream>>>(W0, WT0, flags, 2, F0);
  transw<<<F1, 256, 0, stream>>>(W1, WT1, flags, 3, F1);
  wa_k<<<(F0 + 255) / 256, 256, 0, stream>>>(W0, a1_0, a2_0, a2_1, flags, 2, 4, 5, 7, wa0, F0);
  wa_k<<<(F1 + 255) / 256, 256, 0, stream>>>(W1, a1_1, a2_0, a2_1, flags, 3, 6, 5, 7, wa1, F1);
  gemm_h<<<B * (N1 / 64), 256, 0, stream>>>(x0, WT0, hT0, flags, 0, N1, F0);
  gemm_h<<<B * (N2 / 64), 256, 0, stream>>>(x1, WT1, hT1, flags, 1, N2, F1);
  evec_x<<<B * N1 / 4, 256, 0, stream>>>(x0, wa0, flags, 0, e1_0, e2a, e2c, F0);
  evec_x<<<B * N2 / 4, 256, 0, stream>>>(x1, wa1, flags, 1, e1_1, e2b, e2d, F1);

  const size_t o00 = 0;
  const size_t o01 = (size_t)B * N1 * 256;
  const size_t o10 = o01 + (size_t)B * N1 * 256;
  const size_t o11 = o10 + (size_t)B * N2 * 256;
  att<<<B * (N1 / 64), 256, 0, stream>>>(e1_0, e2a, hT0, adj00, bias, flags, d_out, o00, N1, N1);
  att<<<B * (N1 / 64), 256, 0, stream>>>(e1_0, e2b, hT1, adj01, bias, flags, d_out, o01, N1, N2);
  att<<<B * (N2 / 64), 256, 0, stream>>>(e1_1, e2c, hT0, adj10, bias, flags, d_out, o10, N2, N1);
  att<<<B * (N2 / 64), 256, 0, stream>>>(e1_1, e2d, hT1, adj11, bias, flags, d_out, o11, N2, N2);
}